// Round 14
// baseline (19073.192 us; speedup 1.0000x reference)
//
#include <hip/hip_runtime.h>
#include <hip/hip_fp16.h>

typedef _Float16 h2v __attribute__((ext_vector_type(2)));

__device__ __forceinline__ float fdot2(unsigned int a, unsigned int b, float c) {
    return __builtin_amdgcn_fdot2(__builtin_bit_cast(h2v, a),
                                  __builtin_bit_cast(h2v, b), c, false);
}

#define SCOPE_AGENT __HIP_MEMORY_SCOPE_AGENT
#define SCOPE_SYS   __HIP_MEMORY_SCOPE_SYSTEM

// ---------------- fp32 -> fp16 convert (vectorized x4) ----------------
__global__ __launch_bounds__(256) void k_f2h(const float* __restrict__ src,
                                             __half* __restrict__ dst, int n4) {
    int i = blockIdx.x * 256 + threadIdx.x;
    if (i >= n4) return;
    float4 v = ((const float4*)src)[i];
    union { __half2 h[2]; uint2 u; } o;
    o.h[0] = __halves2half2(__float2half_rn(v.x), __float2half_rn(v.y));
    o.h[1] = __halves2half2(__float2half_rn(v.z), __float2half_rn(v.w));
    ((uint2*)dst)[i] = o.u;
}

__global__ __launch_bounds__(256) void k_bias(const float* __restrict__ a,
                                              const float* __restrict__ b,
                                              float* __restrict__ o) {
    int i = blockIdx.x * 256 + threadIdx.x;
    if (i < 4096) o[i] = a[i] + b[i];
}

// ---------------- x_gates GEMM: C[8192][4096] = A[8192][1024] @ B[4096][1024]^T + bias ----
__global__ __launch_bounds__(256) void k_gemm_xg(const __half* __restrict__ A,
                                                 const __half* __restrict__ B,
                                                 const float* __restrict__ bias,
                                                 __half* __restrict__ C) {
    __shared__ unsigned int As[128][20];
    __shared__ unsigned int Bs[128][20];
    const int tid = threadIdx.x;
    const int tx = tid & 15, ty = tid >> 4;
    const int m0 = blockIdx.x * 128, n0 = blockIdx.y * 128;
    float acc[8][8];
#pragma unroll
    for (int i = 0; i < 8; ++i)
#pragma unroll
        for (int j = 0; j < 8; ++j) acc[i][j] = 0.f;
    const unsigned int* Ag = (const unsigned int*)(A + (size_t)m0 * 1024);
    const unsigned int* Bg = (const unsigned int*)(B + (size_t)n0 * 1024);
    for (int k0 = 0; k0 < 512; k0 += 16) {
        __syncthreads();
#pragma unroll
        for (int j = 0; j < 2; ++j) {
            int qd = j * 256 + tid;
            int row = qd >> 2;
            int c4 = (qd & 3) << 2;
            uint4 va = *(const uint4*)(Ag + (size_t)row * 512 + k0 + c4);
            uint4 vb = *(const uint4*)(Bg + (size_t)row * 512 + k0 + c4);
            *(uint4*)&As[row][c4] = va;
            *(uint4*)&Bs[row][c4] = vb;
        }
        __syncthreads();
#pragma unroll
        for (int k2 = 0; k2 < 16; k2 += 2) {
            unsigned int a0[8], a1[8], b0[8], b1[8];
#pragma unroll
            for (int i = 0; i < 8; ++i) {
                uint2 v = *(const uint2*)&As[ty + 16 * i][k2];
                a0[i] = v.x; a1[i] = v.y;
            }
#pragma unroll
            for (int j = 0; j < 8; ++j) {
                uint2 v = *(const uint2*)&Bs[tx + 16 * j][k2];
                b0[j] = v.x; b1[j] = v.y;
            }
#pragma unroll
            for (int i = 0; i < 8; ++i)
#pragma unroll
                for (int j = 0; j < 8; ++j) {
                    acc[i][j] = fdot2(a0[i], b0[j], acc[i][j]);
                    acc[i][j] = fdot2(a1[i], b1[j], acc[i][j]);
                }
        }
    }
#pragma unroll
    for (int i = 0; i < 8; ++i) {
        int row = m0 + ty + 16 * i;
#pragma unroll
        for (int j = 0; j < 8; ++j) {
            int col = n0 + tx + 16 * j;
            C[(size_t)row * 4096 + col] = __float2half_rn(acc[i][j] + bias[col]);
        }
    }
}

// ---------------- persistent LSTM recurrence ----------------
// XCD-CLUSTERED (r14): launch 256 blocks (1/CU at 152KB LDS); each block reads
// HW_REG_XCC_ID and claims an index on its XCD (device-scope atomics). The
// first XCD to fill 32 claims CASes itself winner; its 32 blocks become slots
// 0..31, all others exit. All pub traffic then stays inside ONE XCD's L2 ->
// agent-scope handshake ops complete at L2 latency (~200-300cy) instead of
// MALL/cross-XCD (~600-900cy). Slot math is symmetric -> identical output
// regardless of which XCD wins. Pigeonhole (256 co-resident blocks, 8 XCDs)
// guarantees a winner; claimers poll until the winner is decided.
// Compute structure = r12 (best measured): slot owns units [32s,32s+32);
// lane (rho=lane>>2, cc=lane&3); segs 0..17 persistent in LDS (144KB), segs
// 18..31 prefetched into registers BEFORE the poll; 4 accumulators.
// Handshake: agent-scope relaxed 4B tagged stores {tag16|h16}, one per unit;
// each poller lane reads ONE 8B word = two tagged halfs = its h2 dword.
__global__ __launch_bounds__(512, 1) void k_lstm(const __half* __restrict__ Whh,
                                                 const __half* __restrict__ xg,
                                                 unsigned int* pub,   // [2][1024]
                                                 int* ctl) {          // [8] counters + [1] winner
    __shared__ uint4 Wp[18][512];          // 144KB persistent weight segs 0..17
    __shared__ unsigned int hs[2][544];    // 8 groups of 64 dwords, stride 68
    __shared__ int sslot;
    const int tid = threadIdx.x;

    if (tid == 0) {
        unsigned xcc;
        asm volatile("s_getreg_b32 %0, hwreg(HW_REG_XCC_ID)" : "=s"(xcc));
        int slot = -1;
        int idx = atomicAdd(&ctl[xcc], 1);
        if (idx < 32) {
            if (idx == 31) atomicCAS(&ctl[8], 0, (int)xcc + 1);
            int win;
            while ((win = __hip_atomic_load(&ctl[8], __ATOMIC_RELAXED, SCOPE_SYS)) == 0)
                __builtin_amdgcn_s_sleep(8);
            if (win == (int)xcc + 1) slot = idx;
        }
        sslot = slot;
    }
    __syncthreads();
    const int b = sslot;                   // worker slot 0..31, or -1
    if (b < 0) return;

    const int w = tid >> 6, lane = tid & 63;
    const int rho = lane >> 2;             // 0..15: gate=rho&3, unit-local=rho>>2
    const int cc = lane & 3;               // k-chunk (256 halfs)
    const int grow = (rho & 3) * 1024 + b * 32 + 4 * w + (rho >> 2);
    const unsigned int* gw = (const unsigned int*)(Whh + (size_t)grow * 1024 + cc * 256);
    // one-time: stage segments 0..17 into LDS (segment i = 4 uints at gw+i*4)
#pragma unroll
    for (int i = 0; i < 18; ++i)
        Wp[i][tid] = *(const uint4*)(gw + i * 4);
    const int soff = (tid >> 6) * 68 + (tid & 63);   // hs slot for h2-dword tid
    const int upub = b * 32 + w * 4 + (lane >> 4);   // unit this lane may publish
    float c_state = 0.f;
    __syncthreads();

    for (int t = 0; t < 8192; ++t) {
        // prefetch this step's streamed weight segments 18..31 (h-independent)
        // BEFORE the poll; pin so the compiler can't sink them past the spin.
        uint4 pv[14];
#pragma unroll
        for (int i = 0; i < 14; ++i)
            pv[i] = *(const uint4*)(gw + (18 + i) * 4);
#pragma unroll
        for (int i = 0; i < 14; ++i)
            asm volatile("" : "+v"(pv[i].x), "+v"(pv[i].y), "+v"(pv[i].z), "+v"(pv[i].w));
        // x_gates prefetch (also h-independent; overlaps the poll)
        float xv = __half2float(xg[(size_t)t * 4096 + grow]);
        unsigned int d = 0;
        if (t > 0) {
            const unsigned long long* src =
                (const unsigned long long*)(pub + (((t - 1) & 1) << 10)) + tid;
            const unsigned tt = (unsigned)t;
            unsigned long long v = __hip_atomic_load(src, __ATOMIC_RELAXED, SCOPE_AGENT);
            unsigned lo = (unsigned)v, hi = (unsigned)(v >> 32);
            while ((lo >> 16) != tt || (hi >> 16) != tt) {
                v = __hip_atomic_load(src, __ATOMIC_RELAXED, SCOPE_AGENT);
                lo = (unsigned)v; hi = (unsigned)(v >> 32);
            }
            d = (lo & 0xffffu) | (hi << 16);
        }
        const int p = t & 1;
        hs[p][soff] = d;
        __syncthreads();                   // the ONLY barrier per step
        float a0 = 0.f, a1 = 0.f, a2 = 0.f, a3 = 0.f;
        const unsigned int* hsp = &hs[p][cc * 136];
        // LDS-resident segments (fast LDS pipe, conflict-free dense reads)
#pragma unroll
        for (int i = 0; i < 18; ++i) {
            uint4 wv = Wp[i][tid];
            uint4 h4 = *(const uint4*)(hsp + (i >> 4) * 68 + ((i & 15) << 2));
            a0 = fdot2(wv.x, h4.x, a0);
            a1 = fdot2(wv.y, h4.y, a1);
            a2 = fdot2(wv.z, h4.z, a2);
            a3 = fdot2(wv.w, h4.w, a3);
        }
        // prefetched register segments (already in VGPRs -- zero load latency)
#pragma unroll
        for (int i = 0; i < 14; ++i) {
            int s = 18 + i;
            uint4 h4 = *(const uint4*)(hsp + (s >> 4) * 68 + ((s & 15) << 2));
            a0 = fdot2(pv[i].x, h4.x, a0);
            a1 = fdot2(pv[i].y, h4.y, a1);
            a2 = fdot2(pv[i].z, h4.z, a2);
            a3 = fdot2(pv[i].w, h4.w, a3);
        }
        float acc = (a0 + a1) + (a2 + a3);
        // reduce over the 4 k-chunks (lane bits 0..1)
        acc += __shfl_xor(acc, 1);
        acc += __shfl_xor(acc, 2);
        acc += xv;
        // gather the 4 gates of unit u = lane>>4 (row rho=4u+g at lane 16u+4g)
        const int base = lane & 48;
        float gi = __shfl(acc, base + 0);
        float gf = __shfl(acc, base + 4);
        float gg = __shfl(acc, base + 8);
        float go = __shfl(acc, base + 12);
        gi = 1.f / (1.f + __expf(-gi));
        gf = 1.f / (1.f + __expf(-gf));
        gg = 2.f / (1.f + __expf(-2.f * gg)) - 1.f;
        go = 1.f / (1.f + __expf(-go));
        c_state = gf * c_state + gi * gg;
        float hval = go * (2.f / (1.f + __expf(-2.f * c_state)) - 1.f);
        // publish: every 16-lane unit-group's lane 0 stores its unit's h
        // (agent scope: pub lines live in this XCD's L2 -- no MALL trip)
        if ((lane & 15) == 0) {
            unsigned val = ((unsigned)(t + 1) << 16) |
                           (unsigned)__half_as_ushort(__float2half_rn(hval));
            __hip_atomic_store(pub + (p << 10) + upub, val,
                               __ATOMIC_RELAXED, SCOPE_AGENT);
        }
    }
}

// ---------------- final projection: out = h_final @ W_out^T + b_out ----------------
__global__ __launch_bounds__(256) void k_proj(const unsigned int* __restrict__ hfin,
                                              const float* __restrict__ Wout,
                                              const float* __restrict__ bout,
                                              float* __restrict__ out) {
    __shared__ float red[256];
    const int o = blockIdx.x, tid = threadIdx.x;
    const float* wr = Wout + (size_t)o * 1024;
    float acc = 0.f;
#pragma unroll
    for (int j = 0; j < 4; ++j) {
        int e = j * 256 + tid;
        unsigned v = hfin[e];              // {tag16 | h16}
        acc += __half2float(__ushort_as_half((unsigned short)(v & 0xffffu))) * wr[e];
    }
    red[tid] = acc;
    __syncthreads();
    for (int s = 128; s > 0; s >>= 1) {
        if (tid < s) red[tid] += red[tid + s];
        __syncthreads();
    }
    if (tid == 0) out[o] = red[0] + bout[o];
}

extern "C" void kernel_launch(void* const* d_in, const int* in_sizes, int n_in,
                              void* d_out, int out_size, void* d_ws, size_t ws_size,
                              hipStream_t stream) {
    const float* input_seq = (const float*)d_in[0];
    const float* W_ih = (const float*)d_in[1];
    const float* W_hh = (const float*)d_in[2];
    const float* b_ih = (const float*)d_in[3];
    const float* b_hh = (const float*)d_in[4];
    const float* W_out = (const float*)d_in[5];
    const float* b_out = (const float*)d_in[6];
    float* out = (float*)d_out;

    char* ws = (char*)d_ws;
    unsigned int* pub = (unsigned int*)ws;                         // [0, 8KB): [2][1024] tagged h
    int* ctl = (int*)(ws + 8192);                                  // [8KB, +64): claim counters + winner
    float* bias = (float*)(ws + 24576);                            // [24KB, 40KB)
    __half* Wih_h = (__half*)(ws + 65536);                         // 8MB
    __half* Whh_h = (__half*)(ws + 65536 + (size_t)8 * 1024 * 1024);   // 8MB
    __half* in_h  = (__half*)(ws + 65536 + (size_t)16 * 1024 * 1024);  // 16MB
    __half* xg    = (__half*)(ws + 65536 + (size_t)32 * 1024 * 1024);  // 64MB

    // clear tags + claim state each call (graph replay determinism)
    hipMemsetAsync(ws, 0, 8320, stream);

    k_f2h<<<8192, 256, 0, stream>>>(input_seq, in_h, 2 * 1024 * 1024);
    k_f2h<<<4096, 256, 0, stream>>>(W_ih, Wih_h, 1024 * 1024);
    k_f2h<<<4096, 256, 0, stream>>>(W_hh, Whh_h, 1024 * 1024);
    k_bias<<<16, 256, 0, stream>>>(b_ih, b_hh, bias);

    dim3 gg(64, 32);
    k_gemm_xg<<<gg, 256, 0, stream>>>(in_h, Wih_h, bias, xg);

    k_lstm<<<256, 512, 0, stream>>>(Whh_h, xg, pub, ctl);

    k_proj<<<1024, 256, 0, stream>>>(pub + 1024, W_out, b_out, out);
}

// Round 15
// 17219.000 us; speedup vs baseline: 1.1077x; 1.1077x over previous
//
#include <hip/hip_runtime.h>
#include <hip/hip_fp16.h>

typedef _Float16 h2v __attribute__((ext_vector_type(2)));

__device__ __forceinline__ float fdot2(unsigned int a, unsigned int b, float c) {
    return __builtin_amdgcn_fdot2(__builtin_bit_cast(h2v, a),
                                  __builtin_bit_cast(h2v, b), c, false);
}

#define SCOPE_SYS __HIP_MEMORY_SCOPE_SYSTEM

// ---------------- fp32 -> fp16 convert (vectorized x4) ----------------
__global__ __launch_bounds__(256) void k_f2h(const float* __restrict__ src,
                                             __half* __restrict__ dst, int n4) {
    int i = blockIdx.x * 256 + threadIdx.x;
    if (i >= n4) return;
    float4 v = ((const float4*)src)[i];
    union { __half2 h[2]; uint2 u; } o;
    o.h[0] = __halves2half2(__float2half_rn(v.x), __float2half_rn(v.y));
    o.h[1] = __halves2half2(__float2half_rn(v.z), __float2half_rn(v.w));
    ((uint2*)dst)[i] = o.u;
}

__global__ __launch_bounds__(256) void k_bias(const float* __restrict__ a,
                                              const float* __restrict__ b,
                                              float* __restrict__ o) {
    int i = blockIdx.x * 256 + threadIdx.x;
    if (i < 4096) o[i] = a[i] + b[i];
}

// ---------------- x_gates GEMM: C[8192][4096] = A[8192][1024] @ B[4096][1024]^T + bias ----
__global__ __launch_bounds__(256) void k_gemm_xg(const __half* __restrict__ A,
                                                 const __half* __restrict__ B,
                                                 const float* __restrict__ bias,
                                                 __half* __restrict__ C) {
    __shared__ unsigned int As[128][20];
    __shared__ unsigned int Bs[128][20];
    const int tid = threadIdx.x;
    const int tx = tid & 15, ty = tid >> 4;
    const int m0 = blockIdx.x * 128, n0 = blockIdx.y * 128;
    float acc[8][8];
#pragma unroll
    for (int i = 0; i < 8; ++i)
#pragma unroll
        for (int j = 0; j < 8; ++j) acc[i][j] = 0.f;
    const unsigned int* Ag = (const unsigned int*)(A + (size_t)m0 * 1024);
    const unsigned int* Bg = (const unsigned int*)(B + (size_t)n0 * 1024);
    for (int k0 = 0; k0 < 512; k0 += 16) {
        __syncthreads();
#pragma unroll
        for (int j = 0; j < 2; ++j) {
            int qd = j * 256 + tid;
            int row = qd >> 2;
            int c4 = (qd & 3) << 2;
            uint4 va = *(const uint4*)(Ag + (size_t)row * 512 + k0 + c4);
            uint4 vb = *(const uint4*)(Bg + (size_t)row * 512 + k0 + c4);
            *(uint4*)&As[row][c4] = va;
            *(uint4*)&Bs[row][c4] = vb;
        }
        __syncthreads();
#pragma unroll
        for (int k2 = 0; k2 < 16; k2 += 2) {
            unsigned int a0[8], a1[8], b0[8], b1[8];
#pragma unroll
            for (int i = 0; i < 8; ++i) {
                uint2 v = *(const uint2*)&As[ty + 16 * i][k2];
                a0[i] = v.x; a1[i] = v.y;
            }
#pragma unroll
            for (int j = 0; j < 8; ++j) {
                uint2 v = *(const uint2*)&Bs[tx + 16 * j][k2];
                b0[j] = v.x; b1[j] = v.y;
            }
#pragma unroll
            for (int i = 0; i < 8; ++i)
#pragma unroll
                for (int j = 0; j < 8; ++j) {
                    acc[i][j] = fdot2(a0[i], b0[j], acc[i][j]);
                    acc[i][j] = fdot2(a1[i], b1[j], acc[i][j]);
                }
        }
    }
#pragma unroll
    for (int i = 0; i < 8; ++i) {
        int row = m0 + ty + 16 * i;
#pragma unroll
        for (int j = 0; j < 8; ++j) {
            int col = n0 + tx + 16 * j;
            C[(size_t)row * 4096 + col] = __float2half_rn(acc[i][j] + bias[col]);
        }
    }
}

// ---------------- persistent LSTM recurrence ----------------
// 32 blocks x 512 threads (8 waves). Block b owns hidden units [32b,32b+32);
// wave w owns units 32b+4w..+4 (4 units x 4 gates = 16 rows).
// Lane (rho=lane>>2, cc=lane&3): row rho (gate=rho&3, unit=rho>>2), k-chunk cc
// of 256 halfs = 32 uint4 weight segments per lane.
// FULL per-step weight residency (r15): segs 0..17 persistent in LDS (144KB,
// loaded once); segs 18..31 persistent in REGISTERS (56 VGPRs, loaded once
// before the t-loop, keep-alive pinned each iteration). r12 re-loaded the 14
// register segs every step -- that drain sat on the pacing block's critical
// path (~300-500cy). 56 VGPRs persistent fits the 256/wave budget (the r6-r8
// failures were pinning all 128). Pin placed BEFORE the poll so any spill
// reloads degrade into the wait window.
// Handshake (r5/r12, best measured): system-scope relaxed 4B tagged stores
// {tag16|h16} one per unit, by the unit's owner lane; each poller lane reads
// ONE 8B word = two tagged halfs = its staged h2 dword. Tight spin, one
// barrier per step.
__global__ __launch_bounds__(512, 1) void k_lstm(const __half* __restrict__ Whh,
                                                 const __half* __restrict__ xg,
                                                 unsigned int* pub) { // [2][1024]
    __shared__ uint4 Wp[18][512];          // 144KB persistent weight segs 0..17
    __shared__ unsigned int hs[2][544];    // 8 groups of 64 dwords, stride 68
    const int tid = threadIdx.x;
    const int b = blockIdx.x;              // 0..31
    const int w = tid >> 6, lane = tid & 63;
    const int rho = lane >> 2;             // 0..15: gate=rho&3, unit-local=rho>>2
    const int cc = lane & 3;               // k-chunk (256 halfs)
    const int grow = (rho & 3) * 1024 + b * 32 + 4 * w + (rho >> 2);
    const unsigned int* gw = (const unsigned int*)(Whh + (size_t)grow * 1024 + cc * 256);
    // one-time: stage segments 0..17 into LDS (segment i = 4 uints at gw+i*4)
#pragma unroll
    for (int i = 0; i < 18; ++i)
        Wp[i][tid] = *(const uint4*)(gw + i * 4);
    // one-time: load streamed segments 18..31 into persistent registers
    uint4 pv[14];
#pragma unroll
    for (int i = 0; i < 14; ++i)
        pv[i] = *(const uint4*)(gw + (18 + i) * 4);
    const int soff = (tid >> 6) * 68 + (tid & 63);   // hs slot for h2-dword tid
    const int upub = b * 32 + w * 4 + (lane >> 4);   // unit this lane may publish
    float c_state = 0.f;
    __syncthreads();

    for (int t = 0; t < 8192; ++t) {
        // keep-alive pin: marks pv modified each iteration so the compiler
        // cannot re-load from memory; placed before the poll so that if the
        // allocator spills anyway, reloads overlap the wait.
#pragma unroll
        for (int i = 0; i < 14; ++i)
            asm volatile("" : "+v"(pv[i].x), "+v"(pv[i].y), "+v"(pv[i].z), "+v"(pv[i].w));
        // x_gates prefetch (h-independent; overlaps the poll)
        float xv = __half2float(xg[(size_t)t * 4096 + grow]);
        unsigned int d = 0;
        if (t > 0) {
            const unsigned long long* src =
                (const unsigned long long*)(pub + (((t - 1) & 1) << 10)) + tid;
            const unsigned tt = (unsigned)t;
            unsigned long long v = __hip_atomic_load(src, __ATOMIC_RELAXED, SCOPE_SYS);
            unsigned lo = (unsigned)v, hi = (unsigned)(v >> 32);
            while ((lo >> 16) != tt || (hi >> 16) != tt) {
                v = __hip_atomic_load(src, __ATOMIC_RELAXED, SCOPE_SYS);
                lo = (unsigned)v; hi = (unsigned)(v >> 32);
            }
            d = (lo & 0xffffu) | (hi << 16);
        }
        const int p = t & 1;
        hs[p][soff] = d;
        __syncthreads();                   // the ONLY barrier per step
        float a0 = 0.f, a1 = 0.f, a2 = 0.f, a3 = 0.f;
        const unsigned int* hsp = &hs[p][cc * 136];
        // LDS-resident segments (fast LDS pipe, conflict-free dense reads)
#pragma unroll
        for (int i = 0; i < 18; ++i) {
            uint4 wv = Wp[i][tid];
            uint4 h4 = *(const uint4*)(hsp + (i >> 4) * 68 + ((i & 15) << 2));
            a0 = fdot2(wv.x, h4.x, a0);
            a1 = fdot2(wv.y, h4.y, a1);
            a2 = fdot2(wv.z, h4.z, a2);
            a3 = fdot2(wv.w, h4.w, a3);
        }
        // register-resident segments (zero load latency)
#pragma unroll
        for (int i = 0; i < 14; ++i) {
            int s = 18 + i;
            uint4 h4 = *(const uint4*)(hsp + (s >> 4) * 68 + ((s & 15) << 2));
            a0 = fdot2(pv[i].x, h4.x, a0);
            a1 = fdot2(pv[i].y, h4.y, a1);
            a2 = fdot2(pv[i].z, h4.z, a2);
            a3 = fdot2(pv[i].w, h4.w, a3);
        }
        float acc = (a0 + a1) + (a2 + a3);
        // reduce over the 4 k-chunks (lane bits 0..1)
        acc += __shfl_xor(acc, 1);
        acc += __shfl_xor(acc, 2);
        acc += xv;
        // gather the 4 gates of unit u = lane>>4 (row rho=4u+g at lane 16u+4g)
        const int base = lane & 48;
        float gi = __shfl(acc, base + 0);
        float gf = __shfl(acc, base + 4);
        float gg = __shfl(acc, base + 8);
        float go = __shfl(acc, base + 12);
        gi = 1.f / (1.f + __expf(-gi));
        gf = 1.f / (1.f + __expf(-gf));
        gg = 2.f / (1.f + __expf(-2.f * gg)) - 1.f;
        go = 1.f / (1.f + __expf(-go));
        c_state = gf * c_state + gi * gg;
        float hval = go * (2.f / (1.f + __expf(-2.f * c_state)) - 1.f);
        // publish: every 16-lane unit-group's lane 0 stores its unit's h
        if ((lane & 15) == 0) {
            unsigned val = ((unsigned)(t + 1) << 16) |
                           (unsigned)__half_as_ushort(__float2half_rn(hval));
            __hip_atomic_store(pub + (p << 10) + upub, val,
                               __ATOMIC_RELAXED, SCOPE_SYS);
        }
    }
}

// ---------------- final projection: out = h_final @ W_out^T + b_out ----------------
__global__ __launch_bounds__(256) void k_proj(const unsigned int* __restrict__ hfin,
                                              const float* __restrict__ Wout,
                                              const float* __restrict__ bout,
                                              float* __restrict__ out) {
    __shared__ float red[256];
    const int o = blockIdx.x, tid = threadIdx.x;
    const float* wr = Wout + (size_t)o * 1024;
    float acc = 0.f;
#pragma unroll
    for (int j = 0; j < 4; ++j) {
        int e = j * 256 + tid;
        unsigned v = hfin[e];              // {tag16 | h16}
        acc += __half2float(__ushort_as_half((unsigned short)(v & 0xffffu))) * wr[e];
    }
    red[tid] = acc;
    __syncthreads();
    for (int s = 128; s > 0; s >>= 1) {
        if (tid < s) red[tid] += red[tid + s];
        __syncthreads();
    }
    if (tid == 0) out[o] = red[0] + bout[o];
}

extern "C" void kernel_launch(void* const* d_in, const int* in_sizes, int n_in,
                              void* d_out, int out_size, void* d_ws, size_t ws_size,
                              hipStream_t stream) {
    const float* input_seq = (const float*)d_in[0];
    const float* W_ih = (const float*)d_in[1];
    const float* W_hh = (const float*)d_in[2];
    const float* b_ih = (const float*)d_in[3];
    const float* b_hh = (const float*)d_in[4];
    const float* W_out = (const float*)d_in[5];
    const float* b_out = (const float*)d_in[6];
    float* out = (float*)d_out;

    char* ws = (char*)d_ws;
    unsigned int* pub = (unsigned int*)ws;                         // [0, 8KB): [2][1024] tagged h
    float* bias = (float*)(ws + 24576);                            // [24KB, 40KB)
    __half* Wih_h = (__half*)(ws + 65536);                         // 8MB
    __half* Whh_h = (__half*)(ws + 65536 + (size_t)8 * 1024 * 1024);   // 8MB
    __half* in_h  = (__half*)(ws + 65536 + (size_t)16 * 1024 * 1024);  // 16MB
    __half* xg    = (__half*)(ws + 65536 + (size_t)32 * 1024 * 1024);  // 64MB

    // clear tags each call (graph replay determinism)
    hipMemsetAsync(ws, 0, 8192, stream);

    k_f2h<<<8192, 256, 0, stream>>>(input_seq, in_h, 2 * 1024 * 1024);
    k_f2h<<<4096, 256, 0, stream>>>(W_ih, Wih_h, 1024 * 1024);
    k_f2h<<<4096, 256, 0, stream>>>(W_hh, Whh_h, 1024 * 1024);
    k_bias<<<16, 256, 0, stream>>>(b_ih, b_hh, bias);

    dim3 gg(64, 32);
    k_gemm_xg<<<gg, 256, 0, stream>>>(in_h, Wih_h, bias, xg);

    k_lstm<<<32, 512, 0, stream>>>(Whh_h, xg, pub);

    k_proj<<<1024, 256, 0, stream>>>(pub + 1024, W_out, b_out, out);
}